// Round 10
// baseline (2083.204 us; speedup 1.0000x reference)
//
#include <hip/hip_runtime.h>

#define D_DIM 1024
#define B_ROWS 65536

typedef unsigned short u16;
typedef __attribute__((ext_vector_type(8))) __bf16 bf16x8;
typedef __attribute__((ext_vector_type(4))) float f32x4;
typedef __attribute__((ext_vector_type(8))) unsigned short u16x8;

typedef const __attribute__((address_space(1))) void* gas_cptr;
typedef __attribute__((address_space(3))) void* las_ptr;

__device__ __forceinline__ u16 f2bf(float f) {
  union { float fv; unsigned int i; } v; v.fv = f;
  return (u16)((v.i + 0x7FFFu + ((v.i >> 16) & 1u)) >> 16);
}
__device__ __forceinline__ float bf2f(u16 u) {
  union { unsigned int i; float f; } v; v.i = ((unsigned int)u) << 16; return v.f;
}

// ---------------------------------------------------------------------------
// PK format (kt-major packed bf16), RT = rows/16:
//   granule(row, col) = ((col>>5)*RT + (row>>4))*64 + ((col>>3)&3)*16 + (row&15)
//   u16 offset = granule*8 + (col&7)    (granule = 8 consecutive cols, 16 B)
// Per (kt, 64-row slab): 256 granules = 4 KB contiguous. Per kt (1024 rows):
// 4096 granules = 64 KB contiguous. Streams perfectly; LDS linear copy gives
// conflict-free b128 frag reads at [rt][g=l4][fr].
// ---------------------------------------------------------------------------

// Fused stage kernel: y = A_pk @ W_pk^T + cb (+R) ; optional LN ; outputs
// f32 row-major and/or PK bf16. Block = 64 rows x 1024 cols, 512 threads.
// RES: 0 none, 1 f32 row-major, 2 PK bf16.
template <int RES, int LN, int OF32, int OPK>
__global__ __launch_bounds__(512, 2) void fused_stage(
    const u16* __restrict__ Ap, const u16* __restrict__ Wp,
    const float* __restrict__ cb, const void* Rp,
    const float* __restrict__ lng, const float* __restrict__ lnb,
    float* of32, u16* opk, int RTA, int RTO)
{
  // LDS: K-loop: sW dbuf 2x64KB @0, sA dbuf 2x4KB @128KB  (136 KB)
  // Epilogue: rbuf 128KB @0 (RES=2), ybuf 64x260 f32 @0, stats 2KB @128KB
  __shared__ __align__(16) u16 smem[69632];
  u16* sW0 = smem;
  u16* sW1 = smem + 32768;
  u16* sA0 = smem + 65536;
  u16* sA1 = smem + 67584;

  const int slab = blockIdx.x;
  const int tid = threadIdx.x;
  const int wave = tid >> 6;
  const int lane = tid & 63;
  const int mg = wave >> 2;        // 0..1 : 32-row group
  const int ns = wave & 3;         // 0..3 : 256-col slice
  const int fr = lane & 15;
  const int l4 = lane >> 4;

  f32x4 acc[2][16] = {};

  // ---------------- K loop: 32 kt-steps of 32 k ----------------
  auto stage = [&](int kt, u16* sw, u16* sa) {
#pragma unroll
    for (int i = 0; i < 8; ++i)
      __builtin_amdgcn_global_load_lds(
          (gas_cptr)(Wp + ((size_t)kt * 4096 + i * 512 + tid) * 8),
          (las_ptr)(sw + ((size_t)(i * 512 + tid)) * 8), 16, 0, 0);
    if (tid < 256)
      __builtin_amdgcn_global_load_lds(
          (gas_cptr)(Ap + (((size_t)kt * RTA + slab * 4) * 64 + tid) * 8),
          (las_ptr)(sa + (size_t)tid * 8), 16, 0, 0);
  };
  auto compute = [&](const u16* sw, const u16* sa) {
    bf16x8 af0 = *(const bf16x8*)&sa[(size_t)(((mg * 2 + 0) * 4 + l4) * 16 + fr) * 8];
    bf16x8 af1 = *(const bf16x8*)&sa[(size_t)(((mg * 2 + 1) * 4 + l4) * 16 + fr) * 8];
#pragma unroll
    for (int nt = 0; nt < 16; ++nt) {
      bf16x8 bf = *(const bf16x8*)&sw[(size_t)(((ns * 16 + nt) * 4 + l4) * 16 + fr) * 8];
      acc[0][nt] = __builtin_amdgcn_mfma_f32_16x16x32_bf16(af0, bf, acc[0][nt], 0, 0, 0);
      acc[1][nt] = __builtin_amdgcn_mfma_f32_16x16x32_bf16(af1, bf, acc[1][nt], 0, 0, 0);
    }
  };

  stage(0, sW0, sA0);
  for (int kt = 0; kt < 32; ++kt) {
    __syncthreads();                    // tile kt resident (drains glds)
    u16* cw = (kt & 1) ? sW1 : sW0;
    u16* ca = (kt & 1) ? sA1 : sA0;
    u16* nw = (kt & 1) ? sW0 : sW1;
    u16* na = (kt & 1) ? sA0 : sA1;
    if (kt + 1 < 32) stage(kt + 1, nw, na);   // overlap with compute
    compute(cw, ca);
  }
  __syncthreads();                      // all LDS reads done; reuse for epilogue

  // ---------------- epilogue ----------------
  float* ybuf = (float*)smem;                       // 64 x 260 f32
  u16* rbuf = smem;                                 // 128 KB (RES=2)
  float* sstats = (float*)(smem + 65536);           // 64 x 4 x 2 f32

  // bias
  if (cb) {
#pragma unroll
    for (int nt = 0; nt < 16; ++nt) {
      const float c = cb[ns * 256 + nt * 16 + fr];
#pragma unroll
      for (int mt = 0; mt < 2; ++mt)
#pragma unroll
        for (int j = 0; j < 4; ++j) acc[mt][nt][j] += c;
    }
  }

  // residual
  if (RES == 1) {
    const float* Rf = (const float*)Rp;
#pragma unroll
    for (int mt = 0; mt < 2; ++mt)
#pragma unroll
      for (int j = 0; j < 4; ++j) {
        const float* rp = Rf + (size_t)(slab * 64 + mg * 32 + mt * 16 + l4 * 4 + j) * D_DIM
                          + ns * 256 + fr;
#pragma unroll
        for (int nt = 0; nt < 16; ++nt) acc[mt][nt][j] += rp[nt * 16];
      }
  }
  if (RES == 2) {
    const u16* Rb = (const u16*)Rp;
#pragma unroll
    for (int i = 0; i < 16; ++i) {
      const int idx = i * 512 + tid;
      const int ktl = idx >> 8, rem = idx & 255;
      __builtin_amdgcn_global_load_lds(
          (gas_cptr)(Rb + (((size_t)ktl * RTA + slab * 4) * 64 + rem) * 8),
          (las_ptr)(rbuf + (size_t)idx * 8), 16, 0, 0);
    }
    __syncthreads();
#pragma unroll
    for (int mt = 0; mt < 2; ++mt) {
      const int rbase = (mg * 2 + mt) * 64;         // (row>>4)*64 within ktl block
#pragma unroll
      for (int nt = 0; nt < 16; ++nt) {
        const int col = ns * 256 + nt * 16 + fr;
        const int ktl = col >> 5, g = (col >> 3) & 3, e = col & 7;
#pragma unroll
        for (int j = 0; j < 4; ++j) {
          const int fr2 = (l4 * 4 + j) & 15;        // row&15 (mt*16 drops out)
          acc[mt][nt][j] += bf2f(rbuf[((size_t)ktl * 256 + rbase + g * 16 + fr2) * 8 + e]);
        }
      }
    }
    __syncthreads();
  }

  // LayerNorm (in-register, stats via shfl + 2KB LDS)
  if (LN) {
    float gv[16], bv[16];
#pragma unroll
    for (int nt = 0; nt < 16; ++nt) {
      gv[nt] = lng[ns * 256 + nt * 16 + fr];
      bv[nt] = lnb[ns * 256 + nt * 16 + fr];
    }
#pragma unroll
    for (int mt = 0; mt < 2; ++mt)
#pragma unroll
      for (int j = 0; j < 4; ++j) {
        float s = 0.f, ss = 0.f;
#pragma unroll
        for (int nt = 0; nt < 16; ++nt) { float v = acc[mt][nt][j]; s += v; ss += v * v; }
        s += __shfl_xor(s, 1, 64);  ss += __shfl_xor(ss, 1, 64);
        s += __shfl_xor(s, 2, 64);  ss += __shfl_xor(ss, 2, 64);
        s += __shfl_xor(s, 4, 64);  ss += __shfl_xor(ss, 4, 64);
        s += __shfl_xor(s, 8, 64);  ss += __shfl_xor(ss, 8, 64);
        if (fr == 0) {
          const int row = mg * 32 + mt * 16 + l4 * 4 + j;
          sstats[(row * 4 + ns) * 2] = s;
          sstats[(row * 4 + ns) * 2 + 1] = ss;
        }
      }
    __syncthreads();
    float mean8[2][4], rstd8[2][4];
#pragma unroll
    for (int mt = 0; mt < 2; ++mt)
#pragma unroll
      for (int j = 0; j < 4; ++j) {
        const int row = mg * 32 + mt * 16 + l4 * 4 + j;
        float S = 0.f, SS = 0.f;
#pragma unroll
        for (int w = 0; w < 4; ++w) {
          S += sstats[(row * 4 + w) * 2];
          SS += sstats[(row * 4 + w) * 2 + 1];
        }
        const float mean = S * (1.f / 1024.f);
        const float var = SS * (1.f / 1024.f) - mean * mean;
        mean8[mt][j] = mean;
        rstd8[mt][j] = rsqrtf(var + 1e-5f);
      }
#pragma unroll
    for (int mt = 0; mt < 2; ++mt)
#pragma unroll
      for (int nt = 0; nt < 16; ++nt)
#pragma unroll
        for (int j = 0; j < 4; ++j)
          acc[mt][nt][j] = (acc[mt][nt][j] - mean8[mt][j]) * rstd8[mt][j] * gv[nt] + bv[nt];
  }
  __syncthreads();

  // output phases: chunk p = cols [p*256, +256); waves ns==p publish to ybuf,
  // then all waves copy out coalesced (f32 row-major and/or PK bf16).
#pragma unroll
  for (int p = 0; p < 4; ++p) {
    if (ns == p) {
#pragma unroll
      for (int mt = 0; mt < 2; ++mt)
#pragma unroll
        for (int j = 0; j < 4; ++j) {
          float* yb = ybuf + (size_t)(mg * 32 + mt * 16 + l4 * 4 + j) * 260 + fr;
#pragma unroll
          for (int nt = 0; nt < 16; ++nt) yb[nt * 16] = acc[mt][nt][j];
        }
    }
    __syncthreads();
    if (OF32) {
      const int row = tid >> 3, cseg = (tid & 7) * 32;
      float* op = of32 + (size_t)(slab * 64 + row) * D_DIM + p * 256 + cseg;
      const float* yb = ybuf + (size_t)row * 260 + cseg;
#pragma unroll
      for (int i = 0; i < 8; ++i) *(f32x4*)(op + i * 4) = *(const f32x4*)(yb + i * 4);
    }
    if (OPK) {
#pragma unroll
      for (int i = 0; i < 4; ++i) {
        const int gid = i * 512 + tid;
        const int ktl = gid >> 8, rem = gid & 255;
        const int rt = rem >> 6, g = (rem >> 4) & 3, fr2 = rem & 15;
        const int row = rt * 16 + fr2;
        const float* yb = ybuf + (size_t)row * 260 + ktl * 32 + g * 8;
        u16x8 o;
#pragma unroll
        for (int t = 0; t < 8; ++t) o[t] = f2bf(yb[t]);
        const size_t gran = ((size_t)(p * 8 + ktl) * RTO + slab * 4 + rt) * 64 + g * 16 + fr2;
        *(u16x8*)&opk[gran * 8] = o;
      }
    }
    __syncthreads();
  }
}

// ---------------- f32 row-major -> PK bf16 (block = 128-row slab) ----------
__global__ __launch_bounds__(256) void pack_pk(const float* __restrict__ src,
                                               u16* __restrict__ dst, int RT)
{
  const int base_row = blockIdx.x * 128;
#pragma unroll 4
  for (int i = 0; i < 64; ++i) {
    const int idx = i * 256 + threadIdx.x;
    const int row = base_row + (idx >> 7);
    const int c8 = idx & 127;
    const float* sp = src + (size_t)row * D_DIM + c8 * 8;
    f32x4 a = *(const f32x4*)sp;
    f32x4 b = *(const f32x4*)(sp + 4);
    u16x8 o;
#pragma unroll
    for (int t = 0; t < 4; ++t) { o[t] = f2bf(a[t]); o[t + 4] = f2bf(b[t]); }
    const size_t gran = ((size_t)(c8 >> 2) * RT + (row >> 4)) * 64 + (c8 & 3) * 16 + (row & 15);
    *(u16x8*)&dst[gran * 8] = o;
  }
}

struct TP4 { const float* s[4]; u16* d[4]; };

// wv (f32 row-major) -> wv^T as PK bf16 (RT=64), batched z=0..3
__global__ __launch_bounds__(256) void transpose_pack(TP4 p) {
  __shared__ float tile[32][33];
  const int z = blockIdx.z;
  const float* src = p.s[z];
  u16* dst = p.d[z];
  const int tx = threadIdx.x & 31, ty = threadIdx.x >> 5;
  const int gx = blockIdx.x * 32, gy = blockIdx.y * 32;
#pragma unroll
  for (int i = 0; i < 4; ++i) {
    const int r = ty + i * 8;
    tile[r][tx] = src[(size_t)(gy + r) * D_DIM + gx + tx];
  }
  __syncthreads();
#pragma unroll
  for (int i = 0; i < 4; ++i) {
    const int drow = gx + ty + i * 8;
    const int dcol = gy + tx;
    const size_t gran = ((size_t)(dcol >> 5) * 64 + (drow >> 4)) * 64
                        + ((dcol >> 3) & 3) * 16 + (drow & 15);
    dst[gran * 8 + (dcol & 7)] = f2bf(tile[tx][ty + i * 8]);
  }
}

struct BiasArgs { const float* wout[4]; const float* bin[4]; const float* bout[4]; };

__global__ __launch_bounds__(256) void bias_kernel(BiasArgs p, float* cb) {
  const int z = blockIdx.z;
  const int i = blockIdx.x * 256 + threadIdx.x;
  const float* wrow = p.wout[z] + (size_t)i * D_DIM;
  const float* bv = p.bin[z] + 2 * D_DIM;
  float s = 0.f;
  for (int j = 0; j < D_DIM; j += 4) {
    f32x4 w4 = *(const f32x4*)&wrow[j];
    f32x4 b4 = *(const f32x4*)&bv[j];
#pragma unroll
    for (int t = 0; t < 4; ++t) s += w4[t] * b4[t];
  }
  cb[(size_t)z * D_DIM + i] = s + p.bout[z][i];
}

extern "C" void kernel_launch(void* const* d_in, const int* in_sizes, int n_in,
                              void* d_out, int out_size, void* d_ws, size_t ws_size,
                              hipStream_t stream) {
  (void)in_sizes; (void)n_in; (void)out_size; (void)ws_size;
  const size_t BD = (size_t)B_ROWS * D_DIM;
  const size_t DD = (size_t)D_DIM * D_DIM;

  const float* feat_local = (const float*)d_in[0];
  const float* feat_tact  = (const float*)d_in[1];
  const float* feat_strat = (const float*)d_in[2];
  const float* w_in[4]  = {(const float*)d_in[3],  (const float*)d_in[7],  (const float*)d_in[11], (const float*)d_in[15]};
  const float* b_in[4]  = {(const float*)d_in[4],  (const float*)d_in[8],  (const float*)d_in[12], (const float*)d_in[16]};
  const float* w_out[4] = {(const float*)d_in[5],  (const float*)d_in[9],  (const float*)d_in[13], (const float*)d_in[17]};
  const float* b_out[4] = {(const float*)d_in[6],  (const float*)d_in[10], (const float*)d_in[14], (const float*)d_in[18]};
  const float* ln_g[3] = {(const float*)d_in[19], (const float*)d_in[21], (const float*)d_in[23]};
  const float* ln_b[3] = {(const float*)d_in[20], (const float*)d_in[22], (const float*)d_in[24]};

  u16* buf0 = (u16*)d_ws;          // PK bf16 stream buffers (128 MB each)
  u16* buf1 = buf0 + BD;
  u16* wvT  = buf1 + BD;           // 4*DD PK
  u16* wobf = wvT + 4 * DD;        // 4*DD PK
  u16* Wc   = wobf + 4 * DD;       // 4*DD PK
  float* cb = (float*)(Wc + 4 * DD);

  float* out = (float*)d_out;
  float* o_loc = out;
  float* o_tac = out + BD;
  float* o_str = out + 2 * BD;

  // 0. pack: local f32 -> PK (buf0); w_out -> PK
  hipLaunchKernelGGL(pack_pk, dim3(512), dim3(256), 0, stream, feat_local, buf0, 4096);
  for (int z = 0; z < 4; ++z)
    hipLaunchKernelGGL(pack_pk, dim3(8), dim3(256), 0, stream, w_out[z], wobf + z * DD, 64);

  // 1. wvT_z = (w_in_z[2D:,:])^T as PK
  TP4 tp;
  for (int z = 0; z < 4; ++z) { tp.s[z] = w_in[z] + 2 * DD; tp.d[z] = wvT + z * DD; }
  hipLaunchKernelGGL(transpose_pack, dim3(32, 32, 4), dim3(256), 0, stream, tp);

  // 2. combined bias c = w_out*bv + b_out (f32)
  BiasArgs ba;
  for (int z = 0; z < 4; ++z) { ba.wout[z] = w_out[z]; ba.bin[z] = b_in[z]; ba.bout[z] = b_out[z]; }
  hipLaunchKernelGGL(bias_kernel, dim3(4, 1, 4), dim3(256), 0, stream, ba, cb);

  // 3. Wc_z = wobf_z @ wvT_z^T -> PK (M=1024 -> 16 slabs)
  for (int z = 0; z < 4; ++z)
    hipLaunchKernelGGL((fused_stage<0, 0, 0, 1>), dim3(16), dim3(512), 0, stream,
                       wobf + z * DD, wvT + z * DD, (const float*)nullptr, (const void*)nullptr,
                       (const float*)nullptr, (const float*)nullptr,
                       (float*)nullptr, Wc + z * DD, 64, 64);

  // 4. S1: tacA = LN1(local@Wc0 + c0 + tact) -> buf1 (PK only)
  hipLaunchKernelGGL((fused_stage<1, 1, 0, 1>), dim3(1024), dim3(512), 0, stream,
                     buf0, Wc + 0 * DD, cb + 0, (const void*)feat_tact,
                     ln_g[0], ln_b[0], (float*)nullptr, buf1, 4096, 4096);

  // 5. S2: strat = LN2(tacA@Wc1 + c1 + strat_in) -> o_str f32 + buf0 PK
  hipLaunchKernelGGL((fused_stage<1, 1, 1, 1>), dim3(1024), dim3(512), 0, stream,
                     buf1, Wc + 1 * DD, cb + 1024, (const void*)feat_strat,
                     ln_g[1], ln_b[1], o_str, buf0, 4096, 4096);

  // 6. S3: tacB = LN3(strat@Wc2 + c2 + tacA) -> o_tac f32 + buf1 PK (in-place resid)
  hipLaunchKernelGGL((fused_stage<2, 1, 1, 1>), dim3(1024), dim3(512), 0, stream,
                     buf0, Wc + 2 * DD, cb + 2048, (const void*)buf1,
                     ln_g[2], ln_b[2], o_tac, buf1, 4096, 4096);

  // 7. S4: loc = local + tacB@Wc3 + c3 -> o_loc f32 (no LN)
  hipLaunchKernelGGL((fused_stage<1, 0, 1, 0>), dim3(1024), dim3(512), 0, stream,
                     buf1, Wc + 3 * DD, cb + 3072, (const void*)feat_local,
                     (const float*)nullptr, (const float*)nullptr, o_loc, (u16*)nullptr,
                     4096, 4096);
}

// Round 11
// 1869.522 us; speedup vs baseline: 1.1143x; 1.1143x over previous
//
#include <hip/hip_runtime.h>

#define D_DIM 1024
#define B_ROWS 65536

typedef unsigned short u16;
typedef __attribute__((ext_vector_type(8))) __bf16 bf16x8;
typedef __attribute__((ext_vector_type(4))) float f32x4;
typedef __attribute__((ext_vector_type(8))) unsigned short u16x8;

typedef const __attribute__((address_space(1))) void* gas_cptr;
typedef __attribute__((address_space(3))) void* las_ptr;

__device__ __forceinline__ u16 f2bf(float f) {
  union { float fv; unsigned int i; } v; v.fv = f;
  return (u16)((v.i + 0x7FFFu + ((v.i >> 16) & 1u)) >> 16);
}
__device__ __forceinline__ float bf2f(u16 u) {
  union { unsigned int i; float f; } v; v.i = ((unsigned int)u) << 16; return v.f;
}

// ---------------------------------------------------------------------------
// PK format (kt-major packed bf16), RT = rows/16:
//   granule(row, col) = ((col>>5)*RT + (row>>4))*64 + ((col>>3)&3)*16 + (row&15)
//   u16 offset = granule*8 + (col&7)
// Per kt (32 cols x all rows) data is contiguous -> perfect HBM streams.
// ---------------------------------------------------------------------------

// Fused stage: y = A_pk @ W_pk^T + cb (+R); optional LN; outputs f32 row-major
// and/or PK bf16. Block = 64 rows x 1024 cols, 512 threads (8 waves).
// launch_bounds(512,1): 2 waves/SIMD -> 256 VGPR cap -> acc[2][16] (128 VGPR)
// does NOT spill (R10's (512,2) forced a 128 cap -> full acc spill).
template <int RES, int LN, int OF32, int OPK>
__global__ __launch_bounds__(512, 1) void fused_stage(
    const u16* __restrict__ Ap, const u16* __restrict__ Wp,
    const float* __restrict__ cb, const void* Rp,
    const float* __restrict__ lng, const float* __restrict__ lnb,
    float* __restrict__ of32, u16* __restrict__ opk, int RTA, int RTO)
{
  __shared__ __align__(16) u16 smem[69632];   // 136 KB
  u16* sW0 = smem;
  u16* sW1 = smem + 32768;
  u16* sA0 = smem + 65536;
  u16* sA1 = smem + 67584;

  const int slab = blockIdx.x;
  const int tid = threadIdx.x;
  const int wave = tid >> 6;
  const int lane = tid & 63;
  const int mg = wave >> 2;        // 0..1 : 32-row group
  const int ns = wave & 3;         // 0..3 : 256-col slice
  const int fr = lane & 15;
  const int l4 = lane >> 4;

  f32x4 acc[2][16] = {};

  auto stage = [&](int kt, u16* sw, u16* sa) {
#pragma unroll
    for (int i = 0; i < 8; ++i)
      __builtin_amdgcn_global_load_lds(
          (gas_cptr)(Wp + ((size_t)kt * 4096 + i * 512 + tid) * 8),
          (las_ptr)(sw + ((size_t)(i * 512 + tid)) * 8), 16, 0, 0);
    if (tid < 256)
      __builtin_amdgcn_global_load_lds(
          (gas_cptr)(Ap + (((size_t)kt * RTA + slab * 4) * 64 + tid) * 8),
          (las_ptr)(sa + (size_t)tid * 8), 16, 0, 0);
  };
  auto compute = [&](const u16* sw, const u16* sa) {
    bf16x8 af0 = *(const bf16x8*)&sa[(size_t)(((mg * 2 + 0) * 4 + l4) * 16 + fr) * 8];
    bf16x8 af1 = *(const bf16x8*)&sa[(size_t)(((mg * 2 + 1) * 4 + l4) * 16 + fr) * 8];
#pragma unroll
    for (int nt = 0; nt < 16; ++nt) {
      bf16x8 bf = *(const bf16x8*)&sw[(size_t)(((ns * 16 + nt) * 4 + l4) * 16 + fr) * 8];
      acc[0][nt] = __builtin_amdgcn_mfma_f32_16x16x32_bf16(af0, bf, acc[0][nt], 0, 0, 0);
      acc[1][nt] = __builtin_amdgcn_mfma_f32_16x16x32_bf16(af1, bf, acc[1][nt], 0, 0, 0);
    }
  };

  stage(0, sW0, sA0);
  for (int kt = 0; kt < 32; ++kt) {
    __syncthreads();                    // tile kt resident (drains glds)
    u16* cw = (kt & 1) ? sW1 : sW0;
    u16* ca = (kt & 1) ? sA1 : sA0;
    u16* nw = (kt & 1) ? sW0 : sW1;
    u16* na = (kt & 1) ? sA0 : sA1;
    if (kt + 1 < 32) stage(kt + 1, nw, na);   // overlap with compute
    compute(cw, ca);
  }
  __syncthreads();                      // all LDS reads done; reuse for epilogue

  // ---------------- epilogue ----------------
  float* ybuf = (float*)smem;                       // 64 x 260 f32 (65 KB)
  u16* rbuf = smem;                                 // 128 KB (RES=2)
  float* sstats = (float*)(smem + 65536);           // byte 131072+: 64x4x2 f32

  if (cb) {
#pragma unroll
    for (int nt = 0; nt < 16; ++nt) {
      const float c = cb[ns * 256 + nt * 16 + fr];
#pragma unroll
      for (int mt = 0; mt < 2; ++mt)
#pragma unroll
        for (int j = 0; j < 4; ++j) acc[mt][nt][j] += c;
    }
  }

  if (RES == 1) {
    const float* Rf = (const float*)Rp;
#pragma unroll
    for (int mt = 0; mt < 2; ++mt)
#pragma unroll
      for (int j = 0; j < 4; ++j) {
        const float* rp = Rf + (size_t)(slab * 64 + mg * 32 + mt * 16 + l4 * 4 + j) * D_DIM
                          + ns * 256 + fr;
#pragma unroll
        for (int nt = 0; nt < 16; ++nt) acc[mt][nt][j] += rp[nt * 16];
      }
  }
  if (RES == 2) {
    const u16* Rb = (const u16*)Rp;
#pragma unroll
    for (int i = 0; i < 16; ++i) {
      const int idx = i * 512 + tid;
      const int ktl = idx >> 8, rem = idx & 255;
      __builtin_amdgcn_global_load_lds(
          (gas_cptr)(Rb + (((size_t)ktl * RTA + slab * 4) * 64 + rem) * 8),
          (las_ptr)(rbuf + (size_t)idx * 8), 16, 0, 0);
    }
    __syncthreads();
#pragma unroll
    for (int mt = 0; mt < 2; ++mt) {
      const int rbase = (mg * 2 + mt) * 64;
#pragma unroll
      for (int nt = 0; nt < 16; ++nt) {
        const int col = ns * 256 + nt * 16 + fr;
        const int ktl = col >> 5, g = (col >> 3) & 3, e = col & 7;
#pragma unroll
        for (int j = 0; j < 4; ++j) {
          const int fr2 = (l4 * 4 + j) & 15;
          acc[mt][nt][j] += bf2f(rbuf[((size_t)ktl * 256 + rbase + g * 16 + fr2) * 8 + e]);
        }
      }
    }
    __syncthreads();
  }

  if (LN) {
#pragma unroll
    for (int mt = 0; mt < 2; ++mt)
#pragma unroll
      for (int j = 0; j < 4; ++j) {
        float s = 0.f, ss = 0.f;
#pragma unroll
        for (int nt = 0; nt < 16; ++nt) { float v = acc[mt][nt][j]; s += v; ss += v * v; }
        s += __shfl_xor(s, 1, 64);  ss += __shfl_xor(ss, 1, 64);
        s += __shfl_xor(s, 2, 64);  ss += __shfl_xor(ss, 2, 64);
        s += __shfl_xor(s, 4, 64);  ss += __shfl_xor(ss, 4, 64);
        s += __shfl_xor(s, 8, 64);  ss += __shfl_xor(ss, 8, 64);
        if (fr == 0) {
          const int row = mg * 32 + mt * 16 + l4 * 4 + j;
          sstats[(row * 4 + ns) * 2] = s;
          sstats[(row * 4 + ns) * 2 + 1] = ss;
        }
      }
    __syncthreads();
#pragma unroll
    for (int mt = 0; mt < 2; ++mt)
#pragma unroll
      for (int j = 0; j < 4; ++j) {
        const int row = mg * 32 + mt * 16 + l4 * 4 + j;
        float S = 0.f, SS = 0.f;
#pragma unroll
        for (int w = 0; w < 4; ++w) {
          S += sstats[(row * 4 + w) * 2];
          SS += sstats[(row * 4 + w) * 2 + 1];
        }
        const float mean = S * (1.f / 1024.f);
        const float var = SS * (1.f / 1024.f) - mean * mean;
        const float rstd = rsqrtf(var + 1e-5f);
#pragma unroll
        for (int nt = 0; nt < 16; ++nt)
          acc[mt][nt][j] = (acc[mt][nt][j] - mean) * rstd;
      }
    // apply gain/bias with minimal live range
#pragma unroll
    for (int nt = 0; nt < 16; ++nt) {
      const float gv = lng[ns * 256 + nt * 16 + fr];
      const float bv = lnb[ns * 256 + nt * 16 + fr];
#pragma unroll
      for (int mt = 0; mt < 2; ++mt)
#pragma unroll
        for (int j = 0; j < 4; ++j)
          acc[mt][nt][j] = acc[mt][nt][j] * gv + bv;
    }
  }
  __syncthreads();

  // output phases: chunk p = cols [p*256, +256)
#pragma unroll
  for (int p = 0; p < 4; ++p) {
    if (ns == p) {
#pragma unroll
      for (int mt = 0; mt < 2; ++mt)
#pragma unroll
        for (int j = 0; j < 4; ++j) {
          float* yb = ybuf + (size_t)(mg * 32 + mt * 16 + l4 * 4 + j) * 260 + fr;
#pragma unroll
          for (int nt = 0; nt < 16; ++nt) yb[nt * 16] = acc[mt][nt][j];
        }
    }
    __syncthreads();
    if (OF32) {
      const int row = tid >> 3, cseg = (tid & 7) * 32;
      float* op = of32 + (size_t)(slab * 64 + row) * D_DIM + p * 256 + cseg;
      const float* yb = ybuf + (size_t)row * 260 + cseg;
#pragma unroll
      for (int i = 0; i < 8; ++i) *(f32x4*)(op + i * 4) = *(const f32x4*)(yb + i * 4);
    }
    if (OPK) {
#pragma unroll
      for (int i = 0; i < 4; ++i) {
        const int gid = i * 512 + tid;
        const int ktl = gid >> 8, rem = gid & 255;
        const int rt = rem >> 6, g = (rem >> 4) & 3, fr2 = rem & 15;
        const int row = rt * 16 + fr2;
        const float* yb = ybuf + (size_t)row * 260 + ktl * 32 + g * 8;
        u16x8 o;
#pragma unroll
        for (int t = 0; t < 8; ++t) o[t] = f2bf(yb[t]);
        const size_t gran = ((size_t)(p * 8 + ktl) * RTO + slab * 4 + rt) * 64 + g * 16 + fr2;
        *(u16x8*)&opk[gran * 8] = o;
      }
    }
    __syncthreads();
  }
}

// ---------------- f32 row-major -> PK bf16 (block = 128-row slab) ----------
__global__ __launch_bounds__(256) void pack_pk(const float* __restrict__ src,
                                               u16* __restrict__ dst, int RT)
{
  const int base_row = blockIdx.x * 128;
#pragma unroll 4
  for (int i = 0; i < 64; ++i) {
    const int idx = i * 256 + threadIdx.x;
    const int row = base_row + (idx >> 7);
    const int c8 = idx & 127;
    const float* sp = src + (size_t)row * D_DIM + c8 * 8;
    f32x4 a = *(const f32x4*)sp;
    f32x4 b = *(const f32x4*)(sp + 4);
    u16x8 o;
#pragma unroll
    for (int t = 0; t < 4; ++t) { o[t] = f2bf(a[t]); o[t + 4] = f2bf(b[t]); }
    const size_t gran = ((size_t)(c8 >> 2) * RT + (row >> 4)) * 64 + (c8 & 3) * 16 + (row & 15);
    *(u16x8*)&dst[gran * 8] = o;
  }
}

struct TP4 { const float* s[4]; u16* d[4]; };

// wv (f32 row-major) -> wv^T as PK bf16 (RT=64), batched z=0..3
__global__ __launch_bounds__(256) void transpose_pack(TP4 p) {
  __shared__ float tile[32][33];
  const int z = blockIdx.z;
  const float* src = p.s[z];
  u16* dst = p.d[z];
  const int tx = threadIdx.x & 31, ty = threadIdx.x >> 5;
  const int gx = blockIdx.x * 32, gy = blockIdx.y * 32;
#pragma unroll
  for (int i = 0; i < 4; ++i) {
    const int r = ty + i * 8;
    tile[r][tx] = src[(size_t)(gy + r) * D_DIM + gx + tx];
  }
  __syncthreads();
#pragma unroll
  for (int i = 0; i < 4; ++i) {
    const int drow = gx + ty + i * 8;
    const int dcol = gy + tx;
    const size_t gran = ((size_t)(dcol >> 5) * 64 + (drow >> 4)) * 64
                        + ((dcol >> 3) & 3) * 16 + (drow & 15);
    dst[gran * 8 + (dcol & 7)] = f2bf(tile[tx][ty + i * 8]);
  }
}

struct BiasArgs { const float* wout[4]; const float* bin[4]; const float* bout[4]; };

__global__ __launch_bounds__(256) void bias_kernel(BiasArgs p, float* cb) {
  const int z = blockIdx.z;
  const int i = blockIdx.x * 256 + threadIdx.x;
  const float* wrow = p.wout[z] + (size_t)i * D_DIM;
  const float* bv = p.bin[z] + 2 * D_DIM;
  float s = 0.f;
  for (int j = 0; j < D_DIM; j += 4) {
    f32x4 w4 = *(const f32x4*)&wrow[j];
    f32x4 b4 = *(const f32x4*)&bv[j];
#pragma unroll
    for (int t = 0; t < 4; ++t) s += w4[t] * b4[t];
  }
  cb[(size_t)z * D_DIM + i] = s + p.bout[z][i];
}

extern "C" void kernel_launch(void* const* d_in, const int* in_sizes, int n_in,
                              void* d_out, int out_size, void* d_ws, size_t ws_size,
                              hipStream_t stream) {
  (void)in_sizes; (void)n_in; (void)out_size; (void)ws_size;
  const size_t BD = (size_t)B_ROWS * D_DIM;
  const size_t DD = (size_t)D_DIM * D_DIM;

  const float* feat_local = (const float*)d_in[0];
  const float* feat_tact  = (const float*)d_in[1];
  const float* feat_strat = (const float*)d_in[2];
  const float* w_in[4]  = {(const float*)d_in[3],  (const float*)d_in[7],  (const float*)d_in[11], (const float*)d_in[15]};
  const float* b_in[4]  = {(const float*)d_in[4],  (const float*)d_in[8],  (const float*)d_in[12], (const float*)d_in[16]};
  const float* w_out[4] = {(const float*)d_in[5],  (const float*)d_in[9],  (const float*)d_in[13], (const float*)d_in[17]};
  const float* b_out[4] = {(const float*)d_in[6],  (const float*)d_in[10], (const float*)d_in[14], (const float*)d_in[18]};
  const float* ln_g[3] = {(const float*)d_in[19], (const float*)d_in[21], (const float*)d_in[23]};
  const float* ln_b[3] = {(const float*)d_in[20], (const float*)d_in[22], (const float*)d_in[24]};

  u16* buf0 = (u16*)d_ws;          // PK bf16 stream buffers (128 MB each)
  u16* buf1 = buf0 + BD;
  u16* wvT  = buf1 + BD;           // 4*DD PK
  u16* wobf = wvT + 4 * DD;        // 4*DD PK
  u16* Wc   = wobf + 4 * DD;       // 4*DD PK
  float* cb = (float*)(Wc + 4 * DD);

  float* out = (float*)d_out;
  float* o_loc = out;
  float* o_tac = out + BD;
  float* o_str = out + 2 * BD;

  // 0. pack: local f32 -> PK (buf0); w_out -> PK
  hipLaunchKernelGGL(pack_pk, dim3(512), dim3(256), 0, stream, feat_local, buf0, 4096);
  for (int z = 0; z < 4; ++z)
    hipLaunchKernelGGL(pack_pk, dim3(8), dim3(256), 0, stream, w_out[z], wobf + z * DD, 64);

  // 1. wvT_z = (w_in_z[2D:,:])^T as PK
  TP4 tp;
  for (int z = 0; z < 4; ++z) { tp.s[z] = w_in[z] + 2 * DD; tp.d[z] = wvT + z * DD; }
  hipLaunchKernelGGL(transpose_pack, dim3(32, 32, 4), dim3(256), 0, stream, tp);

  // 2. combined bias c = w_out*bv + b_out (f32)
  BiasArgs ba;
  for (int z = 0; z < 4; ++z) { ba.wout[z] = w_out[z]; ba.bin[z] = b_in[z]; ba.bout[z] = b_out[z]; }
  hipLaunchKernelGGL(bias_kernel, dim3(4, 1, 4), dim3(256), 0, stream, ba, cb);

  // 3. Wc_z = wobf_z @ wvT_z^T -> PK (M=1024 -> 16 slabs)
  for (int z = 0; z < 4; ++z)
    hipLaunchKernelGGL((fused_stage<0, 0, 0, 1>), dim3(16), dim3(512), 0, stream,
                       wobf + z * DD, wvT + z * DD, (const float*)nullptr, (const void*)nullptr,
                       (const float*)nullptr, (const float*)nullptr,
                       (float*)nullptr, Wc + z * DD, 64, 64);

  // 4. S1: tacA = LN1(local@Wc0 + c0 + tact) -> buf1 (PK only)
  hipLaunchKernelGGL((fused_stage<1, 1, 0, 1>), dim3(1024), dim3(512), 0, stream,
                     buf0, Wc + 0 * DD, cb + 0, (const void*)feat_tact,
                     ln_g[0], ln_b[0], (float*)nullptr, buf1, 4096, 4096);

  // 5. S2: strat = LN2(tacA@Wc1 + c1 + strat_in) -> o_str f32 + buf0 PK
  hipLaunchKernelGGL((fused_stage<1, 1, 1, 1>), dim3(1024), dim3(512), 0, stream,
                     buf1, Wc + 1 * DD, cb + 1024, (const void*)feat_strat,
                     ln_g[1], ln_b[1], o_str, buf0, 4096, 4096);

  // 6. S3: tacB = LN3(strat@Wc2 + c2 + tacA) -> o_tac f32 + buf1 PK (in-place resid)
  hipLaunchKernelGGL((fused_stage<2, 1, 1, 1>), dim3(1024), dim3(512), 0, stream,
                     buf0, Wc + 2 * DD, cb + 2048, (const void*)buf1,
                     ln_g[2], ln_b[2], o_tac, buf1, 4096, 4096);

  // 7. S4: loc = local + tacB@Wc3 + c3 -> o_loc f32 (no LN)
  hipLaunchKernelGGL((fused_stage<1, 0, 1, 0>), dim3(1024), dim3(512), 0, stream,
                     buf1, Wc + 3 * DD, cb + 3072, (const void*)feat_local,
                     (const float*)nullptr, (const float*)nullptr, o_loc, (u16*)nullptr,
                     4096, 4096);
}

// Round 12
// 1792.112 us; speedup vs baseline: 1.1624x; 1.0432x over previous
//
#include <hip/hip_runtime.h>

#define D_DIM 1024
#define B_ROWS 65536

typedef unsigned short u16;
typedef __attribute__((ext_vector_type(8))) __bf16 bf16x8;
typedef __attribute__((ext_vector_type(4))) float f32x4;
typedef __attribute__((ext_vector_type(8))) unsigned short u16x8;

typedef const __attribute__((address_space(1))) void* gas_cptr;
typedef __attribute__((address_space(3))) void* las_ptr;

__device__ __forceinline__ u16 f2bf(float f) {
  union { float fv; unsigned int i; } v; v.fv = f;
  return (u16)((v.i + 0x7FFFu + ((v.i >> 16) & 1u)) >> 16);
}
__device__ __forceinline__ float bf2f(u16 u) {
  union { unsigned int i; float f; } v; v.i = ((unsigned int)u) << 16; return v.f;
}

// ---------------------------------------------------------------------------
// PK format (kt-major packed bf16), RT = rows/16:
//   granule(row, col) = ((col>>5)*RT + (row>>4))*64 + ((col>>3)&3)*16 + (row&15)
//   u16 offset = granule*8 + (col&7)   (granule = 1 row x 8 cols, 16 B)
// A wave reading granules [base..base+64) at lane*16B is a contiguous 1 KB
// coalesced read == exactly one MFMA fragment set. -> W streams L2->registers.
// ---------------------------------------------------------------------------

struct ZArgs { const u16* Ap[4]; const u16* Wp[4]; u16* opk[4]; };

// Fused stage: y = A_pk @ W_pk^T + cb (+R f32 row-major); optional LN; outputs
// f32 row-major and/or PK bf16. Block = 64 rows x 1024 cols, 512 threads.
// W: global->register (no LDS). A: whole 128 KB panel staged once in LDS.
// K-loop has ZERO barriers; compiler-counted vmcnt pipelines W loads.
template <int RES, int LN, int OF32, int OPK>
__global__ __launch_bounds__(512, 1) void fused_stage(
    ZArgs Z, const float* __restrict__ cb, const float* __restrict__ Rf,
    const float* __restrict__ lng, const float* __restrict__ lnb,
    float* __restrict__ of32, int RTA, int RTO)
{
  __shared__ __align__(16) u16 smem[67584];   // 132 KB: A panel 128KB | stats 4KB
  const int z = blockIdx.y;
  const u16* __restrict__ Ap = Z.Ap[z];
  const u16* __restrict__ Wp = Z.Wp[z];
  u16* __restrict__ opk = Z.opk[z];

  const int slab = blockIdx.x;
  const int tid = threadIdx.x;
  const int w = tid >> 6;          // wave 0..7 owns cols [w*128, +128)
  const int lane = tid & 63;
  const int fr = lane & 15;
  const int l4 = lane >> 4;

  // ---- prologue: stage entire A panel (32 kt x 4 KB) into LDS ----
  {
    const int half = tid >> 8;     // 0/1
    const int t8 = tid & 255;
#pragma unroll
    for (int r = 0; r < 16; ++r) {
      const int kt2 = r * 2 + half;
      __builtin_amdgcn_global_load_lds(
          (gas_cptr)(Ap + (((size_t)kt2 * RTA + slab * 4) * 64 + t8) * 8),
          (las_ptr)(smem + ((size_t)kt2 * 256 + t8) * 8), 16, 0, 0);
    }
  }
  __syncthreads();

  // ---- K loop: no barriers; W L2->reg, A LDS->reg ----
  f32x4 acc[4][8] = {};
  const u16* wbase = Wp + ((size_t)(w * 8) * 64 + lane) * 8;
#pragma unroll 2
  for (int kt = 0; kt < 32; ++kt) {
    bf16x8 wf[8];
#pragma unroll
    for (int lt = 0; lt < 8; ++lt)
      wf[lt] = *(const bf16x8*)(wbase + ((size_t)kt * 4096 + lt * 64) * 8);
    bf16x8 af[4];
#pragma unroll
    for (int rt = 0; rt < 4; ++rt)
      af[rt] = *(const bf16x8*)&smem[((size_t)kt * 256 + rt * 64 + lane) * 8];
#pragma unroll
    for (int rt = 0; rt < 4; ++rt)
#pragma unroll
      for (int lt = 0; lt < 8; ++lt)
        acc[rt][lt] = __builtin_amdgcn_mfma_f32_16x16x32_bf16(af[rt], wf[lt], acc[rt][lt], 0, 0, 0);
  }
  __syncthreads();                  // A region now reusable (ybuf)

  // ---- epilogue ----
  float* ybuf = (float*)smem;                   // 64 x 260 f32 (aliases A)
  float* sstats = (float*)(smem + 65536);       // bytes 131072+: 64 x 8 x 2

  if (cb) {
#pragma unroll
    for (int lt = 0; lt < 8; ++lt) {
      const float c = cb[w * 128 + lt * 16 + fr];
#pragma unroll
      for (int rt = 0; rt < 4; ++rt)
#pragma unroll
        for (int j = 0; j < 4; ++j) acc[rt][lt][j] += c;
    }
  }

  if (RES) {
#pragma unroll
    for (int rt = 0; rt < 4; ++rt)
#pragma unroll
      for (int j = 0; j < 4; ++j) {
        const float* rp = Rf + (size_t)(slab * 64 + rt * 16 + l4 * 4 + j) * D_DIM
                          + w * 128 + fr;
#pragma unroll
        for (int lt = 0; lt < 8; ++lt) acc[rt][lt][j] += rp[lt * 16];
      }
  }

  if (LN) {
#pragma unroll
    for (int rt = 0; rt < 4; ++rt)
#pragma unroll
      for (int j = 0; j < 4; ++j) {
        float s = 0.f, ss = 0.f;
#pragma unroll
        for (int lt = 0; lt < 8; ++lt) { float v = acc[rt][lt][j]; s += v; ss += v * v; }
        s += __shfl_xor(s, 1, 64);  ss += __shfl_xor(ss, 1, 64);
        s += __shfl_xor(s, 2, 64);  ss += __shfl_xor(ss, 2, 64);
        s += __shfl_xor(s, 4, 64);  ss += __shfl_xor(ss, 4, 64);
        s += __shfl_xor(s, 8, 64);  ss += __shfl_xor(ss, 8, 64);
        if (fr == 0) {
          const int row = rt * 16 + l4 * 4 + j;
          sstats[(row * 8 + w) * 2] = s;
          sstats[(row * 8 + w) * 2 + 1] = ss;
        }
      }
    __syncthreads();
#pragma unroll
    for (int rt = 0; rt < 4; ++rt)
#pragma unroll
      for (int j = 0; j < 4; ++j) {
        const int row = rt * 16 + l4 * 4 + j;
        float S = 0.f, SS = 0.f;
#pragma unroll
        for (int ww = 0; ww < 8; ++ww) {
          S += sstats[(row * 8 + ww) * 2];
          SS += sstats[(row * 8 + ww) * 2 + 1];
        }
        const float mean = S * (1.f / 1024.f);
        const float var = SS * (1.f / 1024.f) - mean * mean;
        const float rstd = rsqrtf(var + 1e-5f);
#pragma unroll
        for (int lt = 0; lt < 8; ++lt)
          acc[rt][lt][j] = (acc[rt][lt][j] - mean) * rstd;
      }
#pragma unroll
    for (int lt = 0; lt < 8; ++lt) {
      const float gv = lng[w * 128 + lt * 16 + fr];
      const float bv = lnb[w * 128 + lt * 16 + fr];
#pragma unroll
      for (int rt = 0; rt < 4; ++rt)
#pragma unroll
        for (int j = 0; j < 4; ++j)
          acc[rt][lt][j] = acc[rt][lt][j] * gv + bv;
    }
  }
  __syncthreads();

  // output phases: phase p covers cols [p*256,+256) = waves {2p, 2p+1}
#pragma unroll
  for (int p = 0; p < 4; ++p) {
    if ((w >> 1) == p) {
#pragma unroll
      for (int rt = 0; rt < 4; ++rt)
#pragma unroll
        for (int j = 0; j < 4; ++j) {
          float* yb = ybuf + (size_t)(rt * 16 + l4 * 4 + j) * 260 + (w & 1) * 128 + fr;
#pragma unroll
          for (int lt = 0; lt < 8; ++lt) yb[lt * 16] = acc[rt][lt][j];
        }
    }
    __syncthreads();
    if (OF32) {
      const int row = tid >> 3, cseg = (tid & 7) * 32;
      float* op = of32 + (size_t)(slab * 64 + row) * D_DIM + p * 256 + cseg;
      const float* yb = ybuf + (size_t)row * 260 + cseg;
#pragma unroll
      for (int i = 0; i < 8; ++i) *(f32x4*)(op + i * 4) = *(const f32x4*)(yb + i * 4);
    }
    if (OPK) {
#pragma unroll
      for (int i = 0; i < 4; ++i) {
        const int gid = i * 512 + tid;
        const int ktl = gid >> 8, rem = gid & 255;
        const int rt = rem >> 6, g = (rem >> 4) & 3, fr2 = rem & 15;
        const float* yb = ybuf + (size_t)(rt * 16 + fr2) * 260 + ktl * 32 + g * 8;
        f32x4 y0 = *(const f32x4*)yb;
        f32x4 y1 = *(const f32x4*)(yb + 4);
        u16x8 o;
#pragma unroll
        for (int t = 0; t < 4; ++t) { o[t] = f2bf(y0[t]); o[t + 4] = f2bf(y1[t]); }
        const size_t gran = ((size_t)(p * 8 + ktl) * RTO + slab * 4 + rt) * 64 + g * 16 + fr2;
        *(u16x8*)&opk[gran * 8] = o;
      }
    }
    __syncthreads();
  }
}

// ---------------- f32 row-major -> PK bf16 (block = 128-row slab) ----------
__global__ __launch_bounds__(256) void pack_pk(const float* __restrict__ src,
                                               u16* __restrict__ dst, int RT)
{
  const int base_row = blockIdx.x * 128;
#pragma unroll 4
  for (int i = 0; i < 64; ++i) {
    const int idx = i * 256 + threadIdx.x;
    const int row = base_row + (idx >> 7);
    const int c8 = idx & 127;
    const float* sp = src + (size_t)row * D_DIM + c8 * 8;
    f32x4 a = *(const f32x4*)sp;
    f32x4 b = *(const f32x4*)(sp + 4);
    u16x8 o;
#pragma unroll
    for (int t = 0; t < 4; ++t) { o[t] = f2bf(a[t]); o[t + 4] = f2bf(b[t]); }
    const size_t gran = ((size_t)(c8 >> 2) * RT + (row >> 4)) * 64 + (c8 & 3) * 16 + (row & 15);
    *(u16x8*)&dst[gran * 8] = o;
  }
}

struct TP4 { const float* s[4]; u16* d[4]; };

// wv (f32 row-major) -> wv^T as PK bf16 (RT=64), batched z=0..3
__global__ __launch_bounds__(256) void transpose_pack(TP4 p) {
  __shared__ float tile[32][33];
  const int z = blockIdx.z;
  const float* src = p.s[z];
  u16* dst = p.d[z];
  const int tx = threadIdx.x & 31, ty = threadIdx.x >> 5;
  const int gx = blockIdx.x * 32, gy = blockIdx.y * 32;
#pragma unroll
  for (int i = 0; i < 4; ++i) {
    const int r = ty + i * 8;
    tile[r][tx] = src[(size_t)(gy + r) * D_DIM + gx + tx];
  }
  __syncthreads();
#pragma unroll
  for (int i = 0; i < 4; ++i) {
    const int drow = gx + ty + i * 8;
    const int dcol = gy + tx;
    const size_t gran = ((size_t)(dcol >> 5) * 64 + (drow >> 4)) * 64
                        + ((dcol >> 3) & 3) * 16 + (drow & 15);
    dst[gran * 8 + (dcol & 7)] = f2bf(tile[tx][ty + i * 8]);
  }
}

struct BiasArgs { const float* wout[4]; const float* bin[4]; const float* bout[4]; };

__global__ __launch_bounds__(256) void bias_kernel(BiasArgs p, float* cb) {
  const int z = blockIdx.z;
  const int i = blockIdx.x * 256 + threadIdx.x;
  const float* wrow = p.wout[z] + (size_t)i * D_DIM;
  const float* bv = p.bin[z] + 2 * D_DIM;
  float s = 0.f;
  for (int j = 0; j < D_DIM; j += 4) {
    f32x4 w4 = *(const f32x4*)&wrow[j];
    f32x4 b4 = *(const f32x4*)&bv[j];
#pragma unroll
    for (int t = 0; t < 4; ++t) s += w4[t] * b4[t];
  }
  cb[(size_t)z * D_DIM + i] = s + p.bout[z][i];
}

extern "C" void kernel_launch(void* const* d_in, const int* in_sizes, int n_in,
                              void* d_out, int out_size, void* d_ws, size_t ws_size,
                              hipStream_t stream) {
  (void)in_sizes; (void)n_in; (void)out_size; (void)ws_size;
  const size_t BD = (size_t)B_ROWS * D_DIM;
  const size_t DD = (size_t)D_DIM * D_DIM;

  const float* feat_local = (const float*)d_in[0];
  const float* feat_tact  = (const float*)d_in[1];
  const float* feat_strat = (const float*)d_in[2];
  const float* w_in[4]  = {(const float*)d_in[3],  (const float*)d_in[7],  (const float*)d_in[11], (const float*)d_in[15]};
  const float* b_in[4]  = {(const float*)d_in[4],  (const float*)d_in[8],  (const float*)d_in[12], (const float*)d_in[16]};
  const float* w_out[4] = {(const float*)d_in[5],  (const float*)d_in[9],  (const float*)d_in[13], (const float*)d_in[17]};
  const float* b_out[4] = {(const float*)d_in[6],  (const float*)d_in[10], (const float*)d_in[14], (const float*)d_in[18]};
  const float* ln_g[3] = {(const float*)d_in[19], (const float*)d_in[21], (const float*)d_in[23]};
  const float* ln_b[3] = {(const float*)d_in[20], (const float*)d_in[22], (const float*)d_in[24]};

  u16* buf0 = (u16*)d_ws;              // PK bf16 stream buffers (128 MB each)
  u16* buf1 = buf0 + BD;
  float* tacF = (float*)(buf1 + BD);   // tacA f32 row-major (256 MB)
  u16* wvT  = (u16*)(tacF + BD);       // 4*DD PK
  u16* wobf = wvT + 4 * DD;            // 4*DD PK
  u16* Wc   = wobf + 4 * DD;           // 4*DD PK
  float* cb = (float*)(Wc + 4 * DD);

  float* out = (float*)d_out;
  float* o_loc = out;
  float* o_tac = out + BD;
  float* o_str = out + 2 * BD;

  // 0. pack: local f32 -> PK (buf0); w_out -> PK
  hipLaunchKernelGGL(pack_pk, dim3(512), dim3(256), 0, stream, feat_local, buf0, 4096);
  for (int z = 0; z < 4; ++z)
    hipLaunchKernelGGL(pack_pk, dim3(8), dim3(256), 0, stream, w_out[z], wobf + z * DD, 64);

  // 1. wvT_z = (w_in_z[2D:,:])^T as PK
  TP4 tp;
  for (int z = 0; z < 4; ++z) { tp.s[z] = w_in[z] + 2 * DD; tp.d[z] = wvT + z * DD; }
  hipLaunchKernelGGL(transpose_pack, dim3(32, 32, 4), dim3(256), 0, stream, tp);

  // 2. combined bias c = w_out*bv + b_out (f32)
  BiasArgs ba;
  for (int z = 0; z < 4; ++z) { ba.wout[z] = w_out[z]; ba.bin[z] = b_in[z]; ba.bout[z] = b_out[z]; }
  hipLaunchKernelGGL(bias_kernel, dim3(4, 1, 4), dim3(256), 0, stream, ba, cb);

  // 3. Wc_z = wobf_z @ wvT_z^T -> PK (one batched launch, 64 blocks)
  ZArgs zw;
  for (int z = 0; z < 4; ++z) { zw.Ap[z] = wobf + z * DD; zw.Wp[z] = wvT + z * DD; zw.opk[z] = Wc + z * DD; }
  hipLaunchKernelGGL((fused_stage<0, 0, 0, 1>), dim3(16, 4), dim3(512), 0, stream,
                     zw, (const float*)nullptr, (const float*)nullptr,
                     (const float*)nullptr, (const float*)nullptr,
                     (float*)nullptr, 64, 64);

  auto mk = [](const u16* a, const u16* w, u16* o) {
    ZArgs zz;
    for (int z = 0; z < 4; ++z) { zz.Ap[z] = a; zz.Wp[z] = w; zz.opk[z] = o; }
    return zz;
  };

  // 4. S1: tacA = LN1(local@Wc0 + c0 + tact) -> tacF f32 + buf1 PK
  hipLaunchKernelGGL((fused_stage<1, 1, 1, 1>), dim3(1024), dim3(512), 0, stream,
                     mk(buf0, Wc + 0 * DD, buf1), cb + 0, feat_tact,
                     ln_g[0], ln_b[0], tacF, 4096, 4096);

  // 5. S2: strat = LN2(tacA@Wc1 + c1 + strat_in) -> o_str f32 + buf0 PK
  hipLaunchKernelGGL((fused_stage<1, 1, 1, 1>), dim3(1024), dim3(512), 0, stream,
                     mk(buf1, Wc + 1 * DD, buf0), cb + 1024, feat_strat,
                     ln_g[1], ln_b[1], o_str, 4096, 4096);

  // 6. S3: tacB = LN3(strat@Wc2 + c2 + tacA_f32) -> o_tac f32 + buf1 PK
  hipLaunchKernelGGL((fused_stage<1, 1, 1, 1>), dim3(1024), dim3(512), 0, stream,
                     mk(buf0, Wc + 2 * DD, buf1), cb + 2048, tacF,
                     ln_g[2], ln_b[2], o_tac, 4096, 4096);

  // 7. S4: loc = local + tacB@Wc3 + c3 -> o_loc f32 (no LN, no PK)
  hipLaunchKernelGGL((fused_stage<1, 0, 1, 0>), dim3(1024), dim3(512), 0, stream,
                     mk(buf1, Wc + 3 * DD, (u16*)nullptr), cb + 3072, feat_local,
                     (const float*)nullptr, (const float*)nullptr, o_loc, 4096, 4096);
}